// Round 5
// baseline (988.578 us; speedup 1.0000x reference)
//
#include <hip/hip_runtime.h>
#include <math.h>
#include <stdint.h>

#define N_Q 32768
#define K_C 8192
#define D_DIM 512
#define NSTEP 16        // K=512 / BK=32

typedef __attribute__((ext_vector_type(8))) short bf16x8;
typedef __attribute__((ext_vector_type(4))) float f32x4;

typedef const __attribute__((address_space(1))) void gv_t;
typedef __attribute__((address_space(3))) void lv_t;

static __device__ __forceinline__ void gl16(const void* g, void* l) {
    __builtin_amdgcn_global_load_lds((gv_t*)g, (lv_t*)l, 16, 0, 0);
}

static __device__ __forceinline__ unsigned short f2bf(float f) {
    unsigned u = __float_as_uint(f);
    unsigned r = u + 0x7fffu + ((u >> 16) & 1u);
    return (unsigned short)(r >> 16);
}
static __device__ __forceinline__ float bf2f(unsigned short h) {
    return __uint_as_float(((unsigned)h) << 16);
}

// ---------------- kernel 1: normalize emb rows -> wh/wl [k][d] bf16 + wnorm2[k]
__global__ void k_normw(const float* __restrict__ w, unsigned short* __restrict__ wh,
                        unsigned short* __restrict__ wl, float* __restrict__ wnorm2) {
    __shared__ float red[4];
    __shared__ float s_n;
    int k = blockIdx.x;
    int t = threadIdx.x;
    int lane = t & 63, wid = t >> 6;
    float v0 = w[(size_t)k * D_DIM + t];
    float v1 = w[(size_t)k * D_DIM + t + 256];
    float ss = fmaf(v0, v0, v1 * v1);
    for (int off = 32; off; off >>= 1) ss += __shfl_down(ss, off, 64);
    if (lane == 0) red[wid] = ss;
    __syncthreads();
    if (t == 0) s_n = fmaxf(sqrtf(red[0] + red[1] + red[2] + red[3]), 1e-12f);
    __syncthreads();
    float n = s_n;
    float a0 = v0 / n, a1 = v1 / n;
    unsigned short h0 = f2bf(a0), h1 = f2bf(a1);
    wh[(size_t)k * D_DIM + t] = h0;
    wh[(size_t)k * D_DIM + t + 256] = h1;
    wl[(size_t)k * D_DIM + t] = f2bf(a0 - bf2f(h0));
    wl[(size_t)k * D_DIM + t + 256] = f2bf(a1 - bf2f(h1));
    float s2 = fmaf(a0, a0, a1 * a1);
    for (int off = 32; off; off >>= 1) s2 += __shfl_down(s2, off, 64);
    __syncthreads();
    if (lane == 0) red[wid] = s2;
    __syncthreads();
    if (t == 0) wnorm2[k] = red[0] + red[1] + red[2] + red[3];
}

// ---------------- kernel 2: ||x_n|| per row + xh/xl [n][d] bf16
__global__ void k_normx(const float* __restrict__ x, float* __restrict__ xnorm,
                        unsigned short* __restrict__ xh, unsigned short* __restrict__ xl) {
    int wid = threadIdx.x >> 6, lane = threadIdx.x & 63;
    int n = blockIdx.x * 4 + wid;
    const float* xr = x + (size_t)n * D_DIM;
    float v[8];
    float ss = 0.f;
    #pragma unroll
    for (int i = 0; i < 8; ++i) {
        v[i] = xr[lane + i * 64];
        ss = fmaf(v[i], v[i], ss);
    }
    for (int off = 32; off; off >>= 1) ss += __shfl_down(ss, off, 64);
    ss = __shfl(ss, 0, 64);
    float nrm = fmaxf(sqrtf(ss), 1e-12f);
    if (lane == 0) xnorm[n] = nrm;
    #pragma unroll
    for (int i = 0; i < 8; ++i) {
        float a = v[i] / nrm;
        unsigned short h = f2bf(a);
        size_t o = (size_t)n * D_DIM + lane + i * 64;
        xh[o] = h;
        xl[o] = f2bf(a - bf2f(h));
    }
}

// 24-MFMA cluster for one m-pair: 3-product hi/lo reuse
#define MFMA_PAIR(M0, AH0, AL0, AH1, AL1)                                              \
    _Pragma("unroll")                                                                  \
    for (int n = 0; n < 4; ++n) {                                                      \
        acc[M0][n]     = __builtin_amdgcn_mfma_f32_16x16x32_bf16(AH0, bh[n], acc[M0][n], 0, 0, 0);     \
        acc[M0][n]     = __builtin_amdgcn_mfma_f32_16x16x32_bf16(AH0, bl[n], acc[M0][n], 0, 0, 0);     \
        acc[M0][n]     = __builtin_amdgcn_mfma_f32_16x16x32_bf16(AL0, bh[n], acc[M0][n], 0, 0, 0);     \
        acc[M0 + 1][n] = __builtin_amdgcn_mfma_f32_16x16x32_bf16(AH1, bh[n], acc[M0 + 1][n], 0, 0, 0); \
        acc[M0 + 1][n] = __builtin_amdgcn_mfma_f32_16x16x32_bf16(AH1, bl[n], acc[M0 + 1][n], 0, 0, 0); \
        acc[M0 + 1][n] = __builtin_amdgcn_mfma_f32_16x16x32_bf16(AL1, bh[n], acc[M0 + 1][n], 0, 0, 0); \
    }

// ---------------- kernel 3: MFMA score + per-block argmin partials
// dist(n,k) = wnorm2[k] - 2*xn.wk ; dot in 3 bf16 passes (hh+hl+lh),
// fragment reuse: read Ah/Al/Bh/Bl frags once, 3 MFMAs per (m,n) pair.
// Block 256x256, BK=32, 512 thr = 8 waves (2M x 4N), per-wave 128x64.
// LDS: double buffer x 4 regions (Ah,Al,Bh,Bl; 256 rows x 32 d) = 2 x 64KB.
// Chunk swizzle phys = r*4 + (g ^ ((r>>1)&3))  (0-conflict, measured round 2).
// Schedule: 4 phases/step {ds_read cluster -> barrier -> lgkm0 -> setprio(1)
// 24 MFMA setprio(0) -> barrier}; ALL 8 staging gl16 issued in phase 0 of the
// prior step => the step-boundary vmcnt(0) waits on ~4-phase-old loads (free).
__global__ __launch_bounds__(512, 2) void k_score(
    const unsigned short* __restrict__ xh, const unsigned short* __restrict__ xl,
    const unsigned short* __restrict__ wh, const unsigned short* __restrict__ wl,
    const float* __restrict__ wnorm2, unsigned long long* __restrict__ pmin_part)
{
    __shared__ __align__(16) char lds[131072];
    int tid = threadIdx.x;
    int lane = tid & 63, wid = tid >> 6;
    int wm = wid >> 2, wn = wid & 3;
    int c15 = lane & 15, g = lane >> 4;

    // XCD-chunked bijective swizzle (4096 blocks, 4096%8==0)
    int bid = blockIdx.x;
    int swz = (bid & 7) * 512 + (bid >> 3);
    int ktile = swz >> 7;           // 0..31
    int ntile = swz & 127;          // 0..127
    int k0 = ktile * 256;
    int n0 = ntile * 256;

    // fragment LDS byte offsets within a region
    int aoff[8], boff[4];
    #pragma unroll
    for (int m = 0; m < 8; ++m) {
        int r = wm * 128 + m * 16 + c15;
        aoff[m] = (r * 4 + (g ^ ((r >> 1) & 3))) * 16;
    }
    #pragma unroll
    for (int n = 0; n < 4; ++n) {
        int r = wn * 64 + n * 16 + c15;
        boff[n] = (r * 4 + (g ^ ((r >> 1) & 3))) * 16;
    }

    // staging source: phys chunk tid -> row rs, d-group gs (inverse swizzle)
    int rs = tid >> 2;
    int gs = (tid & 3) ^ ((tid >> 3) & 3);
    size_t offA = (size_t)(n0 + rs) * D_DIM + gs * 8;
    size_t offB = (size_t)(k0 + rs) * D_DIM + gs * 8;

    f32x4 acc[8][4];
    #pragma unroll
    for (int m = 0; m < 8; ++m)
        #pragma unroll
        for (int n = 0; n < 4; ++n) acc[m][n] = (f32x4){0.f, 0.f, 0.f, 0.f};

    // prologue: stage step 0 into buf0
    {
        char* nb = lds + tid * 16;
        gl16(xh + offA, nb);
        gl16(xh + offA + 128 * D_DIM, nb + 8192);
        gl16(xl + offA, nb + 16384);
        gl16(xl + offA + 128 * D_DIM, nb + 24576);
        gl16(wh + offB, nb + 32768);
        gl16(wh + offB + 128 * D_DIM, nb + 40960);
        gl16(wl + offB, nb + 49152);
        gl16(wl + offB + 128 * D_DIM, nb + 57344);
    }
    asm volatile("s_waitcnt vmcnt(0)" ::: "memory");
    asm volatile("s_barrier" ::: "memory");

    for (int t = 0; t < NSTEP; ++t) {
        const char* cb = lds + ((t & 1) ? 65536 : 0);
        char* nb = lds + ((t & 1) ? 0 : 65536) + tid * 16;
        int dd = (t + 1) * 32;

        // ---- phase 0: read B frags (8) + A-pair 0 (4); issue ALL staging
        bf16x8 bh[4], bl[4];
        #pragma unroll
        for (int n = 0; n < 4; ++n) {
            bh[n] = *(const bf16x8*)(cb + 32768 + boff[n]);
            bl[n] = *(const bf16x8*)(cb + 49152 + boff[n]);
        }
        bf16x8 a0h = *(const bf16x8*)(cb + aoff[0]);
        bf16x8 a0l = *(const bf16x8*)(cb + 16384 + aoff[0]);
        bf16x8 a1h = *(const bf16x8*)(cb + aoff[1]);
        bf16x8 a1l = *(const bf16x8*)(cb + 16384 + aoff[1]);
        if (t < NSTEP - 1) {
            gl16(xh + offA + dd, nb);
            gl16(xh + offA + dd + 128 * D_DIM, nb + 8192);
            gl16(xl + offA + dd, nb + 16384);
            gl16(xl + offA + dd + 128 * D_DIM, nb + 24576);
            gl16(wh + offB + dd, nb + 32768);
            gl16(wh + offB + dd + 128 * D_DIM, nb + 40960);
            gl16(wl + offB + dd, nb + 49152);
            gl16(wl + offB + dd + 128 * D_DIM, nb + 57344);
        }
        asm volatile("s_barrier" ::: "memory");
        asm volatile("s_waitcnt lgkmcnt(0)" ::: "memory");
        __builtin_amdgcn_sched_barrier(0);
        __builtin_amdgcn_s_setprio(1);
        MFMA_PAIR(0, a0h, a0l, a1h, a1l)
        __builtin_amdgcn_s_setprio(0);
        asm volatile("s_barrier" ::: "memory");

        // ---- phases 1-3: m-pairs (2,3), (4,5), (6,7)
        #pragma unroll
        for (int ph = 1; ph < 4; ++ph) {
            int m0 = ph * 2;
            bf16x8 ph0 = *(const bf16x8*)(cb + aoff[m0]);
            bf16x8 pl0 = *(const bf16x8*)(cb + 16384 + aoff[m0]);
            bf16x8 ph1 = *(const bf16x8*)(cb + aoff[m0 + 1]);
            bf16x8 pl1 = *(const bf16x8*)(cb + 16384 + aoff[m0 + 1]);
            asm volatile("s_barrier" ::: "memory");
            asm volatile("s_waitcnt lgkmcnt(0)" ::: "memory");
            __builtin_amdgcn_sched_barrier(0);
            __builtin_amdgcn_s_setprio(1);
            MFMA_PAIR(m0, ph0, pl0, ph1, pl1)
            __builtin_amdgcn_s_setprio(0);
            if (ph == 3) asm volatile("s_waitcnt vmcnt(0)" ::: "memory");
            asm volatile("s_barrier" ::: "memory");
        }
    }

    // epilogue: dist = wnorm2[k] - 2*dot ; per-row argmin, wn-combined in LDS
    float w2[4];
    #pragma unroll
    for (int n = 0; n < 4; ++n) w2[n] = wnorm2[k0 + wn * 64 + n * 16 + c15];

    unsigned long long* scr = (unsigned long long*)lds;   // 256 rows x 4 wn = 8KB
    #pragma unroll
    for (int m = 0; m < 8; ++m) {
        #pragma unroll
        for (int reg = 0; reg < 4; ++reg) {
            float bv = INFINITY;
            int bk = 0x7fffffff;
            #pragma unroll
            for (int n = 0; n < 4; ++n) {
                float v = fmaf(-2.f, acc[m][n][reg], w2[n]);
                int kk = k0 + wn * 64 + n * 16 + c15;
                if (v < bv || (v == bv && kk < bk)) { bv = v; bk = kk; }
            }
            for (int off = 8; off; off >>= 1) {
                float v2 = __shfl_xor(bv, off, 16);
                int k2 = __shfl_xor(bk, off, 16);
                if (v2 < bv || (v2 == bv && k2 < bk)) { bv = v2; bk = k2; }
            }
            if (c15 == 0) {
                int row = wm * 128 + m * 16 + g * 4 + reg;
                unsigned ub = __float_as_uint(bv);
                ub = (ub & 0x80000000u) ? ~ub : (ub | 0x80000000u);
                scr[row * 4 + wn] = ((unsigned long long)ub << 32) | (unsigned)bk;
            }
        }
    }
    __syncthreads();
    if (tid < 256) {
        unsigned long long v = scr[tid * 4];
        #pragma unroll
        for (int j = 1; j < 4; ++j) {
            unsigned long long u = scr[tid * 4 + j];
            if (u < v) v = u;
        }
        pmin_part[(size_t)ktile * N_Q + n0 + tid] = v;
    }
}

// ---------------- kernel 4: final argmin reduce over the 32 code-tiles
__global__ void k_argmin(const unsigned long long* __restrict__ part, int* __restrict__ idx) {
    int n = blockIdx.x * 256 + threadIdx.x;
    unsigned long long v = part[n];
    #pragma unroll 4
    for (int j = 1; j < 32; ++j) {
        unsigned long long u = part[(size_t)j * N_Q + n];
        if (u < v) v = u;
    }
    idx[n] = (int)(unsigned)(v & 0xffffffffull);
}

// ---------------- kernel 5: gather quantized rows, write output + idxf, loss partials
__global__ void k_gather(const float* __restrict__ x, const float* __restrict__ emb,
                         const float* __restrict__ xnorm, const int* __restrict__ idx,
                         float* __restrict__ qout, float* __restrict__ idxf,
                         float* __restrict__ partials) {
    __shared__ float red[4];
    int t = threadIdx.x, lane = t & 63, wid = t >> 6;
    int n = blockIdx.x * 4 + wid;
    int k = idx[n];
    const float* er = emb + (size_t)k * D_DIM + lane * 8;
    float4 e0 = *(const float4*)er;
    float4 e1 = *(const float4*)(er + 4);
    float ss = e0.x * e0.x + e0.y * e0.y + e0.z * e0.z + e0.w * e0.w
             + e1.x * e1.x + e1.y * e1.y + e1.z * e1.z + e1.w * e1.w;
    for (int off = 32; off; off >>= 1) ss += __shfl_down(ss, off, 64);
    ss = __shfl(ss, 0, 64);
    float nn = fmaxf(sqrtf(ss), 1e-12f);
    float4 q0, q1;
    q0.x = e0.x / nn; q0.y = e0.y / nn; q0.z = e0.z / nn; q0.w = e0.w / nn;
    q1.x = e1.x / nn; q1.y = e1.y / nn; q1.z = e1.z / nn; q1.w = e1.w / nn;

    const float* xr = x + (size_t)n * D_DIM + lane * 8;
    float4 x0 = *(const float4*)xr;
    float4 x1 = *(const float4*)(xr + 4);
    float xn = xnorm[n];
    float d0 = x0.x / xn - q0.x, d1 = x0.y / xn - q0.y;
    float d2 = x0.z / xn - q0.z, d3 = x0.w / xn - q0.w;
    float d4 = x1.x / xn - q1.x, d5 = x1.y / xn - q1.y;
    float d6 = x1.z / xn - q1.z, d7 = x1.w / xn - q1.w;
    float ds = d0 * d0 + d1 * d1 + d2 * d2 + d3 * d3
             + d4 * d4 + d5 * d5 + d6 * d6 + d7 * d7;

    float* qo = qout + (size_t)n * D_DIM + lane * 8;
    *(float4*)qo = q0;
    *(float4*)(qo + 4) = q1;
    if (lane == 0) idxf[n] = (float)k;

    for (int off = 32; off; off >>= 1) ds += __shfl_down(ds, off, 64);
    if (lane == 0) red[wid] = ds;
    __syncthreads();
    if (t == 0) partials[blockIdx.x] = red[0] + red[1] + red[2] + red[3];
}

// ---------------- kernel 6: deterministic final loss reduction
__global__ void k_loss(const float* __restrict__ partials, float* __restrict__ out_loss) {
    __shared__ float red[4];
    int t = threadIdx.x, lane = t & 63, wid = t >> 6;
    float s = 0.f;
    for (int i = t; i < 8192; i += 256) s += partials[i];
    for (int off = 32; off; off >>= 1) s += __shfl_down(s, off, 64);
    if (lane == 0) red[wid] = s;
    __syncthreads();
    if (t == 0)
        out_loss[0] = (red[0] + red[1] + red[2] + red[3]) * (1.25f / ((float)N_Q * (float)D_DIM));
}

extern "C" void kernel_launch(void* const* d_in, const int* in_sizes, int n_in,
                              void* d_out, int out_size, void* d_ws, size_t ws_size,
                              hipStream_t stream) {
    (void)in_sizes; (void)n_in; (void)out_size; (void)ws_size;
    const float* x = (const float*)d_in[0];
    const float* w = (const float*)d_in[1];

    float* out = (float*)d_out;
    float* qout = out;                                  // N*D f32
    float* loss = out + (size_t)N_Q * D_DIM;            // 1
    float* idxf = loss + 1;                             // N

    // xh/xl scratch lives in the qout region (exactly 2*N*D shorts),
    // consumed by k_score, then overwritten by k_gather's final output.
    unsigned short* xh = (unsigned short*)qout;         // N*D shorts
    unsigned short* xl = xh + (size_t)N_Q * D_DIM;      // N*D shorts

    char* ws = (char*)d_ws;
    unsigned short* wh = (unsigned short*)ws;                       // 8MB
    unsigned short* wl = wh + (size_t)K_C * D_DIM;                  // 8MB
    float* wnorm2 = (float*)(wl + (size_t)K_C * D_DIM);             // 32KB
    float* xnorm = wnorm2 + K_C;                                    // 128KB
    unsigned long long* pmin_part = (unsigned long long*)(xnorm + N_Q);  // 32*N u64 = 8MB
    int* idx = (int*)(pmin_part + (size_t)32 * N_Q);                // 128KB
    float* partials = (float*)(idx + N_Q);                          // 32KB

    k_normw<<<K_C, 256, 0, stream>>>(w, wh, wl, wnorm2);
    k_normx<<<N_Q / 4, 256, 0, stream>>>(x, xnorm, xh, xl);
    k_score<<<4096, 512, 0, stream>>>(xh, xl, wh, wl, wnorm2, pmin_part);
    k_argmin<<<N_Q / 256, 256, 0, stream>>>(pmin_part, idx);
    k_gather<<<N_Q / 4, 256, 0, stream>>>(x, w, xnorm, idx, qout, idxf, partials);
    k_loss<<<1, 256, 0, stream>>>(partials, loss);
}

// Round 6
// 804.676 us; speedup vs baseline: 1.2285x; 1.2285x over previous
//
#include <hip/hip_runtime.h>
#include <math.h>
#include <stdint.h>

#define N_Q 32768
#define K_C 8192
#define D_DIM 512
#define NSTEP 16        // K=512 / BK=32
#define KT 64           // k-tiles of 128 codes

typedef __attribute__((ext_vector_type(8))) short bf16x8;
typedef __attribute__((ext_vector_type(4))) float f32x4;

typedef const __attribute__((address_space(1))) void gv_t;
typedef __attribute__((address_space(3))) void lv_t;

static __device__ __forceinline__ void gl16(const void* g, void* l) {
    __builtin_amdgcn_global_load_lds((gv_t*)g, (lv_t*)l, 16, 0, 0);
}

static __device__ __forceinline__ unsigned short f2bf(float f) {
    unsigned u = __float_as_uint(f);
    unsigned r = u + 0x7fffu + ((u >> 16) & 1u);
    return (unsigned short)(r >> 16);
}
static __device__ __forceinline__ float bf2f(unsigned short h) {
    return __uint_as_float(((unsigned)h) << 16);
}
// monotone float->uint map (order-preserving incl. negatives)
static __device__ __forceinline__ unsigned fmap(float f) {
    unsigned u = __float_as_uint(f);
    return (u & 0x80000000u) ? ~u : (u | 0x80000000u);
}
static __device__ __forceinline__ float funmap(unsigned m) {
    return __uint_as_float((m & 0x80000000u) ? (m & 0x7fffffffu) : ~m);
}

// ---------------- kernel 1: normalize emb -> wh bf16, wnorm, wnorm2, rho_w
__global__ void k_normw(const float* __restrict__ w, unsigned short* __restrict__ wh,
                        float* __restrict__ wnorm, float* __restrict__ wnorm2,
                        float* __restrict__ rho_w) {
    __shared__ float red[4];
    __shared__ float s_n;
    int k = blockIdx.x;
    int t = threadIdx.x;
    int lane = t & 63, wid = t >> 6;
    float v0 = w[(size_t)k * D_DIM + t];
    float v1 = w[(size_t)k * D_DIM + t + 256];
    float ss = fmaf(v0, v0, v1 * v1);
    for (int off = 32; off; off >>= 1) ss += __shfl_down(ss, off, 64);
    if (lane == 0) red[wid] = ss;
    __syncthreads();
    if (t == 0) s_n = fmaxf(sqrtf(red[0] + red[1] + red[2] + red[3]), 1e-12f);
    __syncthreads();
    float n = s_n;
    float a0 = v0 / n, a1 = v1 / n;
    unsigned short h0 = f2bf(a0), h1 = f2bf(a1);
    wh[(size_t)k * D_DIM + t] = h0;
    wh[(size_t)k * D_DIM + t + 256] = h1;
    float r0 = a0 - bf2f(h0), r1 = a1 - bf2f(h1);
    // wnorm2 of normalized row + residual norm^2
    float s2 = fmaf(a0, a0, a1 * a1);
    float sr = fmaf(r0, r0, r1 * r1);
    for (int off = 32; off; off >>= 1) s2 += __shfl_down(s2, off, 64);
    for (int off = 32; off; off >>= 1) sr += __shfl_down(sr, off, 64);
    __syncthreads();
    if (lane == 0) { red[wid] = s2; }
    __syncthreads();
    float tot2 = red[0] + red[1] + red[2] + red[3];
    __syncthreads();
    if (lane == 0) { red[wid] = sr; }
    __syncthreads();
    if (t == 0) {
        wnorm[k] = n;
        wnorm2[k] = tot2;
        rho_w[k] = sqrtf(red[0] + red[1] + red[2] + red[3]);
    }
}

// ---------------- kernel 2: rho_w_max = max_k rho_w[k] (deterministic reduce)
__global__ void k_wmax(const float* __restrict__ rho_w, float* __restrict__ rwmax) {
    __shared__ float red[4];
    int t = threadIdx.x, lane = t & 63, wid = t >> 6;
    float m = 0.f;
    for (int i = t; i < K_C; i += 256) m = fmaxf(m, rho_w[i]);
    for (int off = 32; off; off >>= 1) m = fmaxf(m, __shfl_down(m, off, 64));
    if (lane == 0) red[wid] = m;
    __syncthreads();
    if (t == 0) rwmax[0] = fmaxf(fmaxf(red[0], red[1]), fmaxf(red[2], red[3]));
}

// ---------------- kernel 3: xnorm, xh bf16, weps[n] (pruning window)
__global__ void k_normx(const float* __restrict__ x, const float* __restrict__ rwmax,
                        float* __restrict__ xnorm, unsigned short* __restrict__ xh,
                        float* __restrict__ weps) {
    int wid = threadIdx.x >> 6, lane = threadIdx.x & 63;
    int n = blockIdx.x * 4 + wid;
    const float* xr = x + (size_t)n * D_DIM;
    float v[8];
    float ss = 0.f;
    #pragma unroll
    for (int i = 0; i < 8; ++i) {
        v[i] = xr[lane + i * 64];
        ss = fmaf(v[i], v[i], ss);
    }
    for (int off = 32; off; off >>= 1) ss += __shfl_down(ss, off, 64);
    ss = __shfl(ss, 0, 64);
    float nrm = fmaxf(sqrtf(ss), 1e-12f);
    float sr = 0.f;
    #pragma unroll
    for (int i = 0; i < 8; ++i) {
        float a = v[i] / nrm;
        unsigned short h = f2bf(a);
        xh[(size_t)n * D_DIM + lane + i * 64] = h;
        float r = a - bf2f(h);
        sr = fmaf(r, r, sr);
    }
    for (int off = 32; off; off >>= 1) sr += __shfl_down(sr, off, 64);
    if (lane == 0) {
        xnorm[n] = nrm;
        float rho = sqrtf(sr);
        float rwm = rwmax[0];
        // W = 2*eps, eps = 2*(rho_x + (1+rho_x)*rho_w_max) + fp32-accum slack
        weps[n] = 2.f * (2.f * (rho + (1.f + rho) * rwm) + 1.5e-4f);
    }
}

// ---------------- kernel 4: hh-only MFMA score + per-tile argmin + in-window count
// dist_hh(n,k) = wnorm2[k] - 2*xh.wh (fp32 MFMA accum).
// Block 128x128, BK=32, 256 thr = 4 waves (2x2), per-wave 64x64, acc 4x4 frags.
// LDS: double buffer x (Ah 8KB + Bh 8KB) = 32KB, chunk-swizzle
// phys = r*4 + (g ^ ((r>>1)&3))  (0-conflict, measured rounds 2-5).
// Stage t+1 at top of step t; one __syncthreads per step (round-4 scheme at
// 4 blocks/CU occupancy -> m114 inter-block overlap hides the drain).
__global__ __launch_bounds__(256, 2) void k_score(
    const unsigned short* __restrict__ xh, const unsigned short* __restrict__ wh,
    const float* __restrict__ wnorm2, const float* __restrict__ weps,
    unsigned long long* __restrict__ pmin_part, unsigned char* __restrict__ cnt_part)
{
    __shared__ __align__(16) char lds[32768];
    int tid = threadIdx.x;
    int lane = tid & 63, wid = tid >> 6;
    int wm = wid >> 1, wn = wid & 1;
    int ktile = blockIdx.x;         // 0..63
    int k0 = ktile * 128;
    int n0 = blockIdx.y * 128;
    int c15 = lane & 15, g = lane >> 4;

    // fragment LDS byte offsets within a region
    int aoff[4], boff[4];
    #pragma unroll
    for (int f = 0; f < 4; ++f) {
        int ar = wm * 64 + f * 16 + c15;
        aoff[f] = (ar * 4 + (g ^ ((ar >> 1) & 3))) * 16;
        int br = wn * 64 + f * 16 + c15;
        boff[f] = (br * 4 + (g ^ ((br >> 1) & 3))) * 16;
    }

    // staging: thread stages phys chunks tid and tid+256 per region
    int r0 = tid >> 2, g0 = (tid & 3) ^ ((tid >> 3) & 3);
    int p1 = tid + 256;
    int r1 = p1 >> 2, g1 = (p1 & 3) ^ ((p1 >> 3) & 3);
    size_t aA0 = (size_t)(n0 + r0) * D_DIM + g0 * 8;
    size_t aA1 = (size_t)(n0 + r1) * D_DIM + g1 * 8;
    size_t aB0 = (size_t)(k0 + r0) * D_DIM + g0 * 8;
    size_t aB1 = (size_t)(k0 + r1) * D_DIM + g1 * 8;

    f32x4 acc[4][4];
    #pragma unroll
    for (int i = 0; i < 4; ++i)
        #pragma unroll
        for (int j = 0; j < 4; ++j) acc[i][j] = (f32x4){0.f, 0.f, 0.f, 0.f};

    // prologue: stage step 0 into buf0
    gl16(xh + aA0, lds + tid * 16);
    gl16(xh + aA1, lds + 4096 + tid * 16);
    gl16(wh + aB0, lds + 8192 + tid * 16);
    gl16(wh + aB1, lds + 12288 + tid * 16);
    __syncthreads();

    for (int t = 0; t < NSTEP; ++t) {
        if (t < NSTEP - 1) {
            int dd = (t + 1) * 32;
            char* nb = lds + (((t + 1) & 1) ? 16384 : 0);
            gl16(xh + aA0 + dd, nb + tid * 16);
            gl16(xh + aA1 + dd, nb + 4096 + tid * 16);
            gl16(wh + aB0 + dd, nb + 8192 + tid * 16);
            gl16(wh + aB1 + dd, nb + 12288 + tid * 16);
        }
        const char* cb = lds + ((t & 1) ? 16384 : 0);
        bf16x8 ah[4], bh[4];
        #pragma unroll
        for (int f = 0; f < 4; ++f) {
            ah[f] = *(const bf16x8*)(cb + aoff[f]);
            bh[f] = *(const bf16x8*)(cb + 8192 + boff[f]);
        }
        #pragma unroll
        for (int i = 0; i < 4; ++i)
            #pragma unroll
            for (int j = 0; j < 4; ++j)
                acc[i][j] = __builtin_amdgcn_mfma_f32_16x16x32_bf16(ah[i], bh[j], acc[i][j], 0, 0, 0);
        __syncthreads();
    }

    // ---- epilogue: per-row tile min (packed) + count within window
    float w2[4];
    #pragma unroll
    for (int j = 0; j < 4; ++j) w2[j] = wnorm2[k0 + wn * 64 + j * 16 + c15];

    unsigned long long* scr = (unsigned long long*)lds;          // 128*2 u64 = 2KB
    float* tminS = (float*)(lds + 2048);                         // 128
    float* wepsS = tminS + 128;                                  // 128
    int* cntS = (int*)(wepsS + 128);                             // 128

    // pass 1: min over j + 16-lane group; rows = wm*64 + m*16 + g*4 + reg
    #pragma unroll
    for (int m = 0; m < 4; ++m) {
        #pragma unroll
        for (int reg = 0; reg < 4; ++reg) {
            float bv = INFINITY;
            int bk = 0x7fffffff;
            #pragma unroll
            for (int j = 0; j < 4; ++j) {
                float v = fmaf(-2.f, acc[m][j][reg], w2[j]);
                int kk = k0 + wn * 64 + j * 16 + c15;
                if (v < bv || (v == bv && kk < bk)) { bv = v; bk = kk; }
            }
            for (int off = 8; off; off >>= 1) {
                float v2 = __shfl_xor(bv, off, 16);
                int k2 = __shfl_xor(bk, off, 16);
                if (v2 < bv || (v2 == bv && k2 < bk)) { bv = v2; bk = k2; }
            }
            if (c15 == 0) {
                int row = wm * 64 + m * 16 + g * 4 + reg;
                scr[row * 2 + wn] = ((unsigned long long)fmap(bv) << 32) | (unsigned)bk;
            }
        }
    }
    __syncthreads();
    if (tid < 128) {
        unsigned long long a = scr[tid * 2], b = scr[tid * 2 + 1];
        unsigned long long mn = (b < a) ? b : a;
        pmin_part[(size_t)ktile * N_Q + n0 + tid] = mn;
        tminS[tid] = funmap((unsigned)(mn >> 32));
        wepsS[tid] = weps[n0 + tid];
        cntS[tid] = 0;
    }
    __syncthreads();
    // pass 2: count codes with dist <= tilemin + W  (same fmaf -> bitwise same)
    #pragma unroll
    for (int m = 0; m < 4; ++m) {
        #pragma unroll
        for (int reg = 0; reg < 4; ++reg) {
            int row = wm * 64 + m * 16 + g * 4 + reg;
            float thr = tminS[row] + wepsS[row];
            int c = 0;
            #pragma unroll
            for (int j = 0; j < 4; ++j) {
                float v = fmaf(-2.f, acc[m][j][reg], w2[j]);
                c += (v <= thr) ? 1 : 0;
            }
            for (int off = 8; off; off >>= 1) c += __shfl_xor(c, off, 16);
            if (c15 == 0) atomicAdd(&cntS[row], c);
        }
    }
    __syncthreads();
    if (tid < 128) {
        int c = cntS[tid];
        cnt_part[(size_t)ktile * N_Q + n0 + tid] = (unsigned char)(c > 255 ? 255 : c);
    }
}

// ---------------- kernel 5: refine — exact fp32 argmin over pruned candidates
// one wave per row; 64 lanes <-> 64 k-tiles.
__global__ void k_refine(const float* __restrict__ x, const float* __restrict__ emb,
                         const float* __restrict__ xnorm, const float* __restrict__ wnorm,
                         const float* __restrict__ wnorm2, const float* __restrict__ weps,
                         const unsigned long long* __restrict__ pmin_part,
                         const unsigned char* __restrict__ cnt_part,
                         int* __restrict__ idx, float* __restrict__ idxf) {
    int wid = threadIdx.x >> 6, lane = threadIdx.x & 63;
    int n = blockIdx.x * 4 + wid;

    unsigned long long pm = pmin_part[(size_t)lane * N_Q + n];
    int cnt = cnt_part[(size_t)lane * N_Q + n];
    unsigned long long mn = pm;
    for (int off = 32; off; off >>= 1) {
        unsigned long long o = __shfl_xor(mn, off, 64);
        if (o < mn) mn = o;
    }
    float thr = funmap((unsigned)(mn >> 32)) + weps[n];

    // xn in registers: 8 consecutive d per lane
    float xn = xnorm[n];
    const float4* xp = (const float4*)(x + (size_t)n * D_DIM + lane * 8);
    float4 xa = xp[0], xb = xp[1];
    xa.x /= xn; xa.y /= xn; xa.z /= xn; xa.w /= xn;
    xb.x /= xn; xb.y /= xn; xb.z /= xn; xb.w /= xn;

    unsigned long long best = 0xFFFFFFFFFFFFFFFFull;
    unsigned long long mask = __ballot(funmap((unsigned)(pm >> 32)) <= thr);
    while (mask) {
        int t = __ffsll((long long)mask) - 1;
        mask &= mask - 1;
        unsigned long long pmt = __shfl(pm, t);
        int ct = __shfl(cnt, t);
        int kbeg, kend;
        if (ct == 1) { kbeg = (int)(unsigned)(pmt & 0xffffffffull); kend = kbeg + 1; }
        else { kbeg = t * 128; kend = kbeg + 128; }
        for (int k = kbeg; k < kend; ++k) {
            const float4* ep = (const float4*)(emb + (size_t)k * D_DIM + lane * 8);
            float4 e0 = ep[0], e1 = ep[1];
            float dt = xa.x * e0.x + xa.y * e0.y + xa.z * e0.z + xa.w * e0.w
                     + xb.x * e1.x + xb.y * e1.y + xb.z * e1.z + xb.w * e1.w;
            for (int off = 32; off; off >>= 1) dt += __shfl_xor(dt, off, 64);
            float dn = dt / wnorm[k];
            float dist = fmaf(-2.f, dn, wnorm2[k]);
            unsigned long long pk = ((unsigned long long)fmap(dist) << 32) | (unsigned)k;
            if (pk < best) best = pk;
        }
    }
    if (lane == 0) {
        int k = (int)(unsigned)(best & 0xffffffffull);
        idx[n] = k;
        idxf[n] = (float)k;
    }
}

// ---------------- kernel 6: gather quantized rows, write output, loss partials
__global__ void k_gather(const float* __restrict__ x, const float* __restrict__ emb,
                         const float* __restrict__ xnorm, const float* __restrict__ wnorm,
                         const int* __restrict__ idx,
                         float* __restrict__ qout, float* __restrict__ partials) {
    __shared__ float red[4];
    int t = threadIdx.x, lane = t & 63, wid = t >> 6;
    int n = blockIdx.x * 4 + wid;
    int k = idx[n];
    float nn = wnorm[k];
    const float* er = emb + (size_t)k * D_DIM + lane * 8;
    float4 e0 = *(const float4*)er;
    float4 e1 = *(const float4*)(er + 4);
    float4 q0, q1;
    q0.x = e0.x / nn; q0.y = e0.y / nn; q0.z = e0.z / nn; q0.w = e0.w / nn;
    q1.x = e1.x / nn; q1.y = e1.y / nn; q1.z = e1.z / nn; q1.w = e1.w / nn;

    const float* xr = x + (size_t)n * D_DIM + lane * 8;
    float4 x0 = *(const float4*)xr;
    float4 x1 = *(const float4*)(xr + 4);
    float xn = xnorm[n];
    float d0 = x0.x / xn - q0.x, d1 = x0.y / xn - q0.y;
    float d2 = x0.z / xn - q0.z, d3 = x0.w / xn - q0.w;
    float d4 = x1.x / xn - q1.x, d5 = x1.y / xn - q1.y;
    float d6 = x1.z / xn - q1.z, d7 = x1.w / xn - q1.w;
    float ds = d0 * d0 + d1 * d1 + d2 * d2 + d3 * d3
             + d4 * d4 + d5 * d5 + d6 * d6 + d7 * d7;

    float* qo = qout + (size_t)n * D_DIM + lane * 8;
    *(float4*)qo = q0;
    *(float4*)(qo + 4) = q1;

    for (int off = 32; off; off >>= 1) ds += __shfl_down(ds, off, 64);
    if (lane == 0) red[wid] = ds;
    __syncthreads();
    if (t == 0) partials[blockIdx.x] = red[0] + red[1] + red[2] + red[3];
}

// ---------------- kernel 7: deterministic final loss reduction
__global__ void k_loss(const float* __restrict__ partials, float* __restrict__ out_loss) {
    __shared__ float red[4];
    int t = threadIdx.x, lane = t & 63, wid = t >> 6;
    float s = 0.f;
    for (int i = t; i < 8192; i += 256) s += partials[i];
    for (int off = 32; off; off >>= 1) s += __shfl_down(s, off, 64);
    if (lane == 0) red[wid] = s;
    __syncthreads();
    if (t == 0)
        out_loss[0] = (red[0] + red[1] + red[2] + red[3]) * (1.25f / ((float)N_Q * (float)D_DIM));
}

extern "C" void kernel_launch(void* const* d_in, const int* in_sizes, int n_in,
                              void* d_out, int out_size, void* d_ws, size_t ws_size,
                              hipStream_t stream) {
    (void)in_sizes; (void)n_in; (void)out_size; (void)ws_size;
    const float* x = (const float*)d_in[0];
    const float* w = (const float*)d_in[1];

    float* out = (float*)d_out;
    float* qout = out;                                  // N*D f32
    float* loss = out + (size_t)N_Q * D_DIM;            // 1
    float* idxf = loss + 1;                             // N

    // xh bf16 scratch lives in the qout region (N*D shorts = first half),
    // consumed by k_score, then qout overwritten by k_gather.
    unsigned short* xh = (unsigned short*)qout;

    char* ws = (char*)d_ws;
    unsigned short* wh = (unsigned short*)ws;                       // 8 MB
    float* wnorm2 = (float*)(wh + (size_t)K_C * D_DIM);             // 32 KB
    float* wnorm = wnorm2 + K_C;                                    // 32 KB
    float* rho_w = wnorm + K_C;                                     // 32 KB
    float* rwmax = rho_w + K_C;                                     // pad
    float* xnorm = rwmax + 64;                                      // 128 KB
    float* weps = xnorm + N_Q;                                      // 128 KB
    unsigned long long* pmin_part = (unsigned long long*)(weps + N_Q);   // 64*N u64 = 16 MB
    unsigned char* cnt_part = (unsigned char*)(pmin_part + (size_t)KT * N_Q); // 2 MB
    int* idx = (int*)(cnt_part + (size_t)KT * N_Q);                 // 128 KB
    float* partials = (float*)(idx + N_Q);                          // 32 KB

    k_normw<<<K_C, 256, 0, stream>>>(w, wh, wnorm, wnorm2, rho_w);
    k_wmax<<<1, 256, 0, stream>>>(rho_w, rwmax);
    k_normx<<<N_Q / 4, 256, 0, stream>>>(x, rwmax, xnorm, xh, weps);
    dim3 grid(KT, N_Q / 128);
    k_score<<<grid, 256, 0, stream>>>(xh, wh, wnorm2, weps, pmin_part, cnt_part);
    k_refine<<<N_Q / 4, 256, 0, stream>>>(x, w, xnorm, wnorm, wnorm2, weps,
                                          pmin_part, cnt_part, idx, idxf);
    k_gather<<<N_Q / 4, 256, 0, stream>>>(x, w, xnorm, wnorm, idx, qout, partials);
    k_loss<<<1, 256, 0, stream>>>(partials, loss);
}